// Round 2
// baseline (8053.339 us; speedup 1.0000x reference)
//
#include <hip/hip_runtime.h>

#define S_ 2048
#define D_ 64
#define H_ 12
#define TQ 8

// One block per (h-major bh pair, 8-query tile). 256 threads = 4 waves.
// Streaming structure: per 256-key chunk, each thread computes 8 logits
// (its key x 8 queries), exps them, and deposits UNNORMALIZED e into a
// 64 KB LDS buffer pe[8][2048] while accumulating row sums. One barrier,
// then attn store (normalized, nontemporal) and PV both read from pe.
// PV accumulates unnormalized e*v; inv[] is applied once at the end.
__global__ __launch_bounds__(256, 2) void sdpa_bias_kernel(
    const float* __restrict__ qm, const float* __restrict__ km,
    const float* __restrict__ vm, const int* __restrict__ mask,
    const float* __restrict__ bias, float* __restrict__ out,
    float* __restrict__ attn)
{
    const int tid  = threadIdx.x;
    const int lane = tid & 63;
    const int wid  = tid >> 6;
    const int qt  = blockIdx.x;         // 0..255  (query tile)
    const int bhp = blockIdx.y;         // h-major: bhp = h*2 + b  (bias L3 reuse)
    const int h  = bhp >> 1;
    const int b  = bhp & 1;
    const int bh = b * H_ + h;
    const int q0 = qt * TQ;

    __shared__ float4 qs4[TQ][D_/4];    // 2 KB   q/T tile
    __shared__ float  pe[TQ][S_];       // 64 KB  unnormalized exp(logit)
    __shared__ float  obuf[4][TQ][D_];  // 8 KB   per-wave PV partials
    __shared__ float  wsum[4][TQ];      // per-wave row sums

    // ---- stage Q tile, pre-scaled by 1/T ----
    if (tid < TQ * (D_/4)) {            // 128 float4 loads
        int row = tid >> 4;
        int c   = tid & 15;
        const float4* qp = (const float4*)(qm + ((size_t)bh * S_ + q0 + row) * D_);
        float4 t = qp[c];
        t.x *= 0.125f; t.y *= 0.125f; t.z *= 0.125f; t.w *= 0.125f;
        qs4[row][c] = t;
    }
    __syncthreads();

    const float4* kp = (const float4*)(km + (size_t)bh * S_ * D_);
    const float*  bp = bias + (size_t)h * S_ * S_ + (size_t)q0 * S_;
    const int*    mp = mask + (size_t)b * S_;

    // ---- phase 1: stream key chunks; only 8 logit regs live at a time ----
    float s[TQ];
    #pragma unroll
    for (int qq = 0; qq < TQ; ++qq) s[qq] = 0.f;

    for (int j = 0; j < 8; ++j) {
        const int kk = j * 256 + tid;
        float l[TQ];
        #pragma unroll
        for (int qq = 0; qq < TQ; ++qq) l[qq] = 0.f;
        const float4* kr = kp + (size_t)kk * (D_/4);
        #pragma unroll
        for (int dc = 0; dc < D_/4; ++dc) {
            float4 kv = kr[dc];
            #pragma unroll
            for (int qq = 0; qq < TQ; ++qq) {
                float4 qv = qs4[qq][dc];   // wave-uniform broadcast read
                l[qq] = fmaf(qv.w, kv.w,
                        fmaf(qv.z, kv.z,
                        fmaf(qv.y, kv.y,
                        fmaf(qv.x, kv.x, l[qq]))));
            }
        }
        const int m = mp[kk];
        #pragma unroll
        for (int qq = 0; qq < TQ; ++qq) {
            // plain (cacheable) bias load: b=0/b=1 pair shares it via L2/L3
            float e = m ? __expf(l[qq] + bp[(size_t)qq * S_ + kk]) : 0.f;
            pe[qq][kk] = e;                // 2-lanes/bank write: conflict-free
            s[qq] += e;
        }
    }

    // ---- row-sum reduction: wave shuffle, then cross-wave via LDS ----
    #pragma unroll
    for (int qq = 0; qq < TQ; ++qq) {
        float t = s[qq];
        #pragma unroll
        for (int off = 32; off > 0; off >>= 1) t += __shfl_xor(t, off, 64);
        s[qq] = t;
    }
    if (lane == 0) {
        #pragma unroll
        for (int qq = 0; qq < TQ; ++qq) wsum[wid][qq] = s[qq];
    }
    __syncthreads();                     // also publishes all pe writes
    float inv[TQ];
    #pragma unroll
    for (int qq = 0; qq < TQ; ++qq)
        inv[qq] = 1.0f / (wsum[0][qq] + wsum[1][qq] + wsum[2][qq] + wsum[3][qq]);

    // ---- phase 2: normalized attn store (streaming writes) ----
    float* arow = attn + ((size_t)bh * S_ + q0) * S_;
    #pragma unroll
    for (int j = 0; j < 8; ++j) {
        const int kk = j * 256 + tid;
        #pragma unroll
        for (int qq = 0; qq < TQ; ++qq)
            __builtin_nontemporal_store(pe[qq][kk] * inv[qq],
                                        arow + (size_t)qq * S_ + kk);
    }

    // ---- phase 3: PV. wave wid owns keys [wid*512, +512), d = lane ----
    float oacc[TQ];
    #pragma unroll
    for (int qq = 0; qq < TQ; ++qq) oacc[qq] = 0.f;

    const int kb = wid * 512;
    const float* vp = vm + (size_t)bh * S_ * D_ + (size_t)kb * D_ + lane;
    for (int g = 0; g < 128; ++g) {
        float4 pb[TQ];
        #pragma unroll
        for (int qq = 0; qq < TQ; ++qq)
            pb[qq] = *(const float4*)&pe[qq][kb + g*4];   // broadcast b128
        #pragma unroll
        for (int u = 0; u < 4; ++u) {
            float vv = vp[(size_t)(g*4 + u) * D_];        // coalesced 256B/wave
            #pragma unroll
            for (int qq = 0; qq < TQ; ++qq) {
                float pv = (u==0)?pb[qq].x:(u==1)?pb[qq].y:(u==2)?pb[qq].z:pb[qq].w;
                oacc[qq] = fmaf(pv, vv, oacc[qq]);
            }
        }
    }

    // ---- normalize PV partials (pe held UNnormalized e), reduce, store ----
    #pragma unroll
    for (int qq = 0; qq < TQ; ++qq) obuf[wid][qq][lane] = oacc[qq] * inv[qq];
    __syncthreads();
    float* ob = out + ((size_t)bh * S_ + q0) * D_;
    for (int id = tid; id < TQ*D_; id += 256) {
        int qq = id >> 6, d = id & 63;
        ob[(size_t)qq * D_ + d] = obuf[0][qq][d] + obuf[1][qq][d]
                                + obuf[2][qq][d] + obuf[3][qq][d];
    }
}

extern "C" void kernel_launch(void* const* d_in, const int* in_sizes, int n_in,
                              void* d_out, int out_size, void* d_ws, size_t ws_size,
                              hipStream_t stream) {
    const float* q    = (const float*)d_in[0];
    const float* k    = (const float*)d_in[1];
    const float* v    = (const float*)d_in[2];
    const int*   mask = (const int*)d_in[3];
    const float* bias = (const float*)d_in[4];
    float* out  = (float*)d_out;
    float* attn = out + (size_t)2 * H_ * S_ * D_;   // B*H*S*D elements, then attn

    dim3 grid(S_ / TQ, 2 * H_);
    sdpa_bias_kernel<<<grid, 256, 0, stream>>>(q, k, v, mask, bias, out, attn);
}